// Round 7
// baseline (170.078 us; speedup 1.0000x reference)
//
#include <hip/hip_runtime.h>

#define NB 8
#define NC 256
#define FH 64
#define FW 64
#define NS (FH * FW)          // 4096 spatial positions per batch
#define NSAMP 131072
#define MARGIN_F 12.0f

#define BUCKET_CAP NSAMP                 // absolutely safe per-bucket capacity
#define GATHER_BLOCKS 4096               // 512 block-groups per XCD bucket
#define GROUPS_PER_XCD (GATHER_BLOCKS / 8)
#define OCTETS_PER_BLOCK 32
#define BUCKET_STRIDE (GROUPS_PER_XCD * OCTETS_PER_BLOCK)   // 16384

typedef float vfloat2 __attribute__((ext_vector_type(2)));

// ---------------------------------------------------------------------------
// fp8 e4m3 (OCP) pack via gfx950 HW converts.
// ---------------------------------------------------------------------------
__device__ __forceinline__ unsigned pack4_fp8(float f0, float f1, float f2, float f3)
{
    int r = __builtin_amdgcn_cvt_pk_fp8_f32(f0, f1, 0, false);  // bytes 0,1
    r     = __builtin_amdgcn_cvt_pk_fp8_f32(f2, f3, r, true);   // bytes 2,3
    return (unsigned)r;
}

// ---------------------------------------------------------------------------
// Kernel 1: batched transpose (B, C, S) fp32 -> (B, S, C) fp8 e4m3.
// 64x64 tile, float4 reads, LDS fp32 tile padded to 65 (<=2-way bank alias,
// free on gfx950), 4-byte packed fp8 writes. (unchanged from R5 — passed)
// ---------------------------------------------------------------------------
__global__ __launch_bounds__(256) void transpose_to_bsc_fp8(
    const float* __restrict__ in0, const float* __restrict__ in1,
    unsigned char* __restrict__ out0, unsigned char* __restrict__ out1)
{
    __shared__ float tile[64][65];

    const int which = blockIdx.z >> 3;
    const int b     = blockIdx.z & 7;
    const float* __restrict__ in  = which ? in1 : in0;
    unsigned char* __restrict__ out = which ? out1 : out0;

    const int s0 = blockIdx.x * 64;
    const int c0 = blockIdx.y * 64;
    const int t  = threadIdx.x;

    const float* __restrict__ inb  = in  + (size_t)b * NC * NS;
    unsigned char* __restrict__ outb = out + (size_t)b * NS * NC;

    const int g   = t >> 4;          // 0..15
    const int sl4 = (t & 15) << 2;   // 0,4,...,60
#pragma unroll
    for (int pass = 0; pass < 4; ++pass) {
        const int cl = pass * 16 + g;
        const float4 v = *(const float4*)&inb[(size_t)(c0 + cl) * NS + (s0 + sl4)];
        tile[sl4 + 0][cl] = v.x;
        tile[sl4 + 1][cl] = v.y;
        tile[sl4 + 2][cl] = v.z;
        tile[sl4 + 3][cl] = v.w;
    }
    __syncthreads();

    const int cl4 = (t & 15) << 2;
#pragma unroll
    for (int pass = 0; pass < 4; ++pass) {
        const int sl = pass * 16 + (t >> 4);
        const unsigned w = pack4_fp8(tile[sl][cl4 + 0], tile[sl][cl4 + 1],
                                     tile[sl][cl4 + 2], tile[sl][cl4 + 3]);
        *(unsigned*)&outb[(size_t)(s0 + sl) * NC + (c0 + cl4)] = w;
    }
}

// ---------------------------------------------------------------------------
// Kernel 2: bucket samples by batch index. One thread per sample (512x256).
// LDS histogram -> one global atomic per (block, bucket) -> scatter packed
// records {a_off, p_off, n_off} into per-bucket regions.
// ---------------------------------------------------------------------------
__global__ __launch_bounds__(256) void bucket_samples(
    const int*  __restrict__ batch_idx,
    const int2* __restrict__ anchor_yx,
    const int2* __restrict__ pos_yx,
    const int2* __restrict__ neg_yx,
    uint4* __restrict__ recs,
    unsigned* __restrict__ cursors)
{
    const int i = blockIdx.x * 256 + threadIdx.x;   // exactly NSAMP threads
    const int  b  = batch_idx[i];
    const int2 ay = anchor_yx[i];
    const int2 py = pos_yx[i];
    const int2 ny = neg_yx[i];

    const unsigned aoff = (unsigned)(b * NS + ay.x * FW + ay.y);
    const unsigned poff = (unsigned)(b * NS + py.x * FW + py.y);
    const unsigned noff = (unsigned)(b * NS + ny.x * FW + ny.y);

    __shared__ unsigned hist[8], base[8];
    if (threadIdx.x < 8) hist[threadIdx.x] = 0;
    __syncthreads();
    const unsigned rank = atomicAdd(&hist[b], 1u);          // LDS atomic
    __syncthreads();
    if (threadIdx.x < 8)
        base[threadIdx.x] = atomicAdd(&cursors[threadIdx.x], hist[threadIdx.x]);
    __syncthreads();
    recs[(size_t)b * BUCKET_CAP + base[b] + rank] = make_uint4(aoff, poff, noff, 0u);
}

// ---------------------------------------------------------------------------
// Kernel 3: XCD-local gather + triplet loss.
// blockIdx%8 selects the bucket; with round-robin block->XCD dispatch each
// XCD touches only its batch's 2 MB of fp8 staging (fits 4 MB L2).
// One sample per 8-lane octet, 6 independent 16B loads (R5's proven MLP).
// ---------------------------------------------------------------------------
__device__ __forceinline__ void acc_u32(unsigned a, unsigned p, unsigned n, float& d)
{
    const vfloat2 a0 = __builtin_amdgcn_cvt_pk_f32_fp8(a, false);
    const vfloat2 a1 = __builtin_amdgcn_cvt_pk_f32_fp8(a, true);
    const vfloat2 p0 = __builtin_amdgcn_cvt_pk_f32_fp8(p, false);
    const vfloat2 p1 = __builtin_amdgcn_cvt_pk_f32_fp8(p, true);
    const vfloat2 n0 = __builtin_amdgcn_cvt_pk_f32_fp8(n, false);
    const vfloat2 n1 = __builtin_amdgcn_cvt_pk_f32_fp8(n, true);
    float t;
    t = a0.x - p0.x; d += t * t;  t = a0.x - n0.x; d -= t * t;
    t = a0.y - p0.y; d += t * t;  t = a0.y - n0.y; d -= t * t;
    t = a1.x - p1.x; d += t * t;  t = a1.x - n1.x; d -= t * t;
    t = a1.y - p1.y; d += t * t;  t = a1.y - n1.y; d -= t * t;
}

__device__ __forceinline__ void acc_quad(uint4 a, uint4 p, uint4 n, float& d)
{
    acc_u32(a.x, p.x, n.x, d);
    acc_u32(a.y, p.y, n.y, d);
    acc_u32(a.z, p.z, n.z, d);
    acc_u32(a.w, p.w, n.w, d);
}

__global__ __launch_bounds__(256) void triplet_gather_xcd(
    const uint4* __restrict__ tq,   // (B*S) fp8 vectors, 16 uint4 each
    const uint4* __restrict__ tk,
    const uint4* __restrict__ recs,
    const unsigned* __restrict__ cursors,
    float* __restrict__ out)
{
    const int t   = threadIdx.x;
    const int ol  = t & 7;           // lane within octet
    const int oct = t >> 3;          // octet id in block, 0..31
    const int x   = blockIdx.x & 7;  // bucket == XCD (heuristic; correct regardless)
    const int g   = blockIdx.x >> 3; // group within bucket, 0..511

    const unsigned cnt = cursors[x];
    const uint4* __restrict__ brecs = recs + (size_t)x * BUCKET_CAP;

    float acc = 0.0f;
    for (unsigned j = (unsigned)(g * OCTETS_PER_BLOCK + oct); j < cnt; j += BUCKET_STRIDE) {
        const uint4 r = brecs[j];                 // 8 lanes broadcast-load 16B
        const size_t ab = (size_t)r.x * 16;       // uint4 units
        const size_t pb = (size_t)r.y * 16;
        const size_t nb = (size_t)r.z * 16;

        const uint4 A0 = tq[ab + ol];
        const uint4 A1 = tq[ab + 8 + ol];
        const uint4 P0 = tk[pb + ol];
        const uint4 P1 = tk[pb + 8 + ol];
        const uint4 N0 = tk[nb + ol];
        const uint4 N1 = tk[nb + 8 + ol];

        float d = 0.0f;
        acc_quad(A0, P0, N0, d);
        acc_quad(A1, P1, N1, d);
#pragma unroll
        for (int m = 1; m < 8; m <<= 1) d += __shfl_xor(d, m, 64);
        acc += (ol == 0) ? fmaxf(d + MARGIN_F, 0.0f) : 0.0f;
    }

    // wave reduce (non-zero only on ol==0 lanes)
#pragma unroll
    for (int m = 1; m < 64; m <<= 1) acc += __shfl_xor(acc, m, 64);
    __shared__ float wsum[4];
    if ((t & 63) == 0) wsum[t >> 6] = acc;
    __syncthreads();
    if (t == 0) {
        const float invN = 1.0f / (1e-6f + (float)NSAMP);
        atomicAdd(out, (wsum[0] + wsum[1] + wsum[2] + wsum[3]) * invN);
    }
}

// ---------------------------------------------------------------------------
// Fallback (ws too small): direct strided gather in original layout.
// ---------------------------------------------------------------------------
__global__ __launch_bounds__(256) void triplet_direct(
    const float* __restrict__ q, const float* __restrict__ k,
    const int*  __restrict__ batch_idx,
    const int2* __restrict__ anchor_yx,
    const int2* __restrict__ pos_yx,
    const int2* __restrict__ neg_yx,
    float* __restrict__ out)
{
    const int lane   = threadIdx.x & 63;
    const int wid    = threadIdx.x >> 6;
    const int gwave  = blockIdx.x * 4 + wid;
    const int nwaves = gridDim.x * 4;

    float wsum = 0.0f;
    for (int i = gwave; i < NSAMP; i += nwaves) {
        const int  b  = batch_idx[i];
        const int2 ay = anchor_yx[i];
        const int2 py = pos_yx[i];
        const int2 ny = neg_yx[i];

        const size_t base = (size_t)b * NC * NS;
        const int sa = ay.x * FW + ay.y;
        const int sp = py.x * FW + py.y;
        const int sn = ny.x * FW + ny.y;

        float d = 0.0f;
#pragma unroll
        for (int kk = 0; kk < 4; ++kk) {
            const int c = lane + 64 * kk;
            const float av = q[base + (size_t)c * NS + sa];
            const float pv = k[base + (size_t)c * NS + sp];
            const float nv = k[base + (size_t)c * NS + sn];
            float t;
            t = av - pv; d += t * t;
            t = av - nv; d -= t * t;
        }
#pragma unroll
        for (int m = 1; m < 64; m <<= 1) d += __shfl_xor(d, m, 64);
        if (lane == 0) wsum += fmaxf(d + MARGIN_F, 0.0f);
    }

    __shared__ float bsum[4];
    if (lane == 0) bsum[wid] = wsum;
    __syncthreads();
    if (threadIdx.x == 0) {
        const float invN = 1.0f / (1e-6f + (float)NSAMP);
        atomicAdd(out, (bsum[0] + bsum[1] + bsum[2] + bsum[3]) * invN);
    }
}

extern "C" void kernel_launch(void* const* d_in, const int* in_sizes, int n_in,
                              void* d_out, int out_size, void* d_ws, size_t ws_size,
                              hipStream_t stream)
{
    const float* sketch = (const float*)d_in[0];
    const float* refk   = (const float*)d_in[1];
    const int*   bidx   = (const int*)d_in[2];
    const int2*  ayx    = (const int2*)d_in[3];
    const int2*  pyx    = (const int2*)d_in[4];
    const int2*  nyx    = (const int2*)d_in[5];
    float*       out    = (float*)d_out;

    // zero the scalar accumulator (poisoned 0xAA)
    (void)hipMemsetAsync(out, 0, sizeof(float), stream);

    const size_t tensor_elems = (size_t)NB * NC * NS;               // 8M (8 MB fp8 each)
    const size_t recs_bytes   = (size_t)NB * BUCKET_CAP * sizeof(uint4); // 16 MB
    const size_t need = 2 * tensor_elems + recs_bytes + 8 * sizeof(unsigned);

    if (ws_size >= need) {
        unsigned char* tq = (unsigned char*)d_ws;
        unsigned char* tk = tq + tensor_elems;
        uint4* recs       = (uint4*)(tk + tensor_elems);
        unsigned* cursors = (unsigned*)((unsigned char*)recs + recs_bytes);

        (void)hipMemsetAsync(cursors, 0, 8 * sizeof(unsigned), stream);

        dim3 tgrid(NS / 64, NC / 64, 16);   // 64 x 4 x 16
        transpose_to_bsc_fp8<<<tgrid, 256, 0, stream>>>(sketch, refk, tq, tk);

        bucket_samples<<<NSAMP / 256, 256, 0, stream>>>(
            bidx, ayx, pyx, nyx, recs, cursors);

        triplet_gather_xcd<<<GATHER_BLOCKS, 256, 0, stream>>>(
            (const uint4*)tq, (const uint4*)tk, recs, cursors, out);
    } else {
        triplet_direct<<<4096, 256, 0, stream>>>(
            sketch, refk, bidx, ayx, pyx, nyx, out);
    }
}

// Round 8
// 152.276 us; speedup vs baseline: 1.1169x; 1.1169x over previous
//
#include <hip/hip_runtime.h>

#define NB 8
#define NC 256
#define FH 64
#define FW 64
#define NS (FH * FW)          // 4096 spatial positions per batch
#define NSAMP 131072
#define MARGIN_F 12.0f

#define BUCKET_CAP NSAMP
#define GATHER_BLOCKS 2048               // one full-occupancy round (32 waves/CU)
#define CHUNK 32                         // records per cursor grab (1 per octet)

typedef float vfloat2 __attribute__((ext_vector_type(2)));

// ---------------------------------------------------------------------------
// fp8 e4m3 (OCP) pack via gfx950 HW converts.
// ---------------------------------------------------------------------------
__device__ __forceinline__ unsigned pack4_fp8(float f0, float f1, float f2, float f3)
{
    int r = __builtin_amdgcn_cvt_pk_fp8_f32(f0, f1, 0, false);  // bytes 0,1
    r     = __builtin_amdgcn_cvt_pk_fp8_f32(f2, f3, r, true);   // bytes 2,3
    return (unsigned)r;
}

// ---------------------------------------------------------------------------
// Kernel 1: batched transpose (B, C, S) fp32 -> (B, S, C) fp8 e4m3.
// (unchanged from R5/R7 — verified)
// ---------------------------------------------------------------------------
__global__ __launch_bounds__(256) void transpose_to_bsc_fp8(
    const float* __restrict__ in0, const float* __restrict__ in1,
    unsigned char* __restrict__ out0, unsigned char* __restrict__ out1)
{
    __shared__ float tile[64][65];

    const int which = blockIdx.z >> 3;
    const int b     = blockIdx.z & 7;
    const float* __restrict__ in  = which ? in1 : in0;
    unsigned char* __restrict__ out = which ? out1 : out0;

    const int s0 = blockIdx.x * 64;
    const int c0 = blockIdx.y * 64;
    const int t  = threadIdx.x;

    const float* __restrict__ inb  = in  + (size_t)b * NC * NS;
    unsigned char* __restrict__ outb = out + (size_t)b * NS * NC;

    const int g   = t >> 4;          // 0..15
    const int sl4 = (t & 15) << 2;   // 0,4,...,60
#pragma unroll
    for (int pass = 0; pass < 4; ++pass) {
        const int cl = pass * 16 + g;
        const float4 v = *(const float4*)&inb[(size_t)(c0 + cl) * NS + (s0 + sl4)];
        tile[sl4 + 0][cl] = v.x;
        tile[sl4 + 1][cl] = v.y;
        tile[sl4 + 2][cl] = v.z;
        tile[sl4 + 3][cl] = v.w;
    }
    __syncthreads();

    const int cl4 = (t & 15) << 2;
#pragma unroll
    for (int pass = 0; pass < 4; ++pass) {
        const int sl = pass * 16 + (t >> 4);
        const unsigned w = pack4_fp8(tile[sl][cl4 + 0], tile[sl][cl4 + 1],
                                     tile[sl][cl4 + 2], tile[sl][cl4 + 3]);
        *(unsigned*)&outb[(size_t)(s0 + sl) * NC + (c0 + cl4)] = w;
    }
}

// ---------------------------------------------------------------------------
// Kernel 2: bucket samples by batch index (unchanged from R7 — verified).
// ---------------------------------------------------------------------------
__global__ __launch_bounds__(256) void bucket_samples(
    const int*  __restrict__ batch_idx,
    const int2* __restrict__ anchor_yx,
    const int2* __restrict__ pos_yx,
    const int2* __restrict__ neg_yx,
    uint4* __restrict__ recs,
    unsigned* __restrict__ counts)
{
    const int i = blockIdx.x * 256 + threadIdx.x;   // exactly NSAMP threads
    const int  b  = batch_idx[i];
    const int2 ay = anchor_yx[i];
    const int2 py = pos_yx[i];
    const int2 ny = neg_yx[i];

    const unsigned aoff = (unsigned)(b * NS + ay.x * FW + ay.y);
    const unsigned poff = (unsigned)(b * NS + py.x * FW + py.y);
    const unsigned noff = (unsigned)(b * NS + ny.x * FW + ny.y);

    __shared__ unsigned hist[8], base[8];
    if (threadIdx.x < 8) hist[threadIdx.x] = 0;
    __syncthreads();
    const unsigned rank = atomicAdd(&hist[b], 1u);          // LDS atomic
    __syncthreads();
    if (threadIdx.x < 8)
        base[threadIdx.x] = atomicAdd(&counts[threadIdx.x], hist[threadIdx.x]);
    __syncthreads();
    recs[(size_t)b * BUCKET_CAP + base[b] + rank] = make_uint4(aoff, poff, noff, 0u);
}

// ---------------------------------------------------------------------------
// Kernel 3: XCD-local gather via REAL XCC_ID + work-stealing cursors.
// Each block drains its own XCD's bucket (2 MB working set, fits 4 MB L2),
// then sweeps the other 7 buckets for leftovers (correct for ANY XCC value
// since consumption goes through atomic cursors).
// ---------------------------------------------------------------------------
__device__ __forceinline__ void acc_u32(unsigned a, unsigned p, unsigned n, float& d)
{
    const vfloat2 a0 = __builtin_amdgcn_cvt_pk_f32_fp8(a, false);
    const vfloat2 a1 = __builtin_amdgcn_cvt_pk_f32_fp8(a, true);
    const vfloat2 p0 = __builtin_amdgcn_cvt_pk_f32_fp8(p, false);
    const vfloat2 p1 = __builtin_amdgcn_cvt_pk_f32_fp8(p, true);
    const vfloat2 n0 = __builtin_amdgcn_cvt_pk_f32_fp8(n, false);
    const vfloat2 n1 = __builtin_amdgcn_cvt_pk_f32_fp8(n, true);
    float t;
    t = a0.x - p0.x; d += t * t;  t = a0.x - n0.x; d -= t * t;
    t = a0.y - p0.y; d += t * t;  t = a0.y - n0.y; d -= t * t;
    t = a1.x - p1.x; d += t * t;  t = a1.x - n1.x; d -= t * t;
    t = a1.y - p1.y; d += t * t;  t = a1.y - n1.y; d -= t * t;
}

__device__ __forceinline__ void acc_quad(uint4 a, uint4 p, uint4 n, float& d)
{
    acc_u32(a.x, p.x, n.x, d);
    acc_u32(a.y, p.y, n.y, d);
    acc_u32(a.z, p.z, n.z, d);
    acc_u32(a.w, p.w, n.w, d);
}

__global__ __launch_bounds__(256) void triplet_gather_xcd(
    const uint4* __restrict__ tq,   // (B*S) fp8 vectors, 16 uint4 each
    const uint4* __restrict__ tk,
    const uint4* __restrict__ recs,
    const unsigned* __restrict__ counts,  // 8 bucket fill counts
    unsigned* __restrict__ ccur,          // 8 consume cursors, stride 32 uints
    float* __restrict__ partials)
{
    const int t   = threadIdx.x;
    const int ol  = t & 7;           // lane within octet
    const int oct = t >> 3;          // octet id in block, 0..31

    unsigned xcc;
    asm volatile("s_getreg_b32 %0, hwreg(20, 0, 32)" : "=s"(xcc));  // HW_REG_XCC_ID
    const int myx = (int)(xcc & 7u);

    __shared__ unsigned sbase;
    float acc = 0.0f;

    for (int r = 0; r < 8; ++r) {                 // own bucket first, then sweep
        const int x = (myx + r) & 7;
        const unsigned cnt = counts[x];
        const uint4* __restrict__ brecs = recs + (size_t)x * BUCKET_CAP;

        for (;;) {
            __syncthreads();
            if (t == 0) sbase = atomicAdd(&ccur[x * 32], (unsigned)CHUNK);
            __syncthreads();
            const unsigned base = sbase;
            if (base >= cnt) break;

            const unsigned j = base + (unsigned)oct;
            if (j < cnt) {
                const uint4 rec = brecs[j];
                const size_t ab = (size_t)rec.x * 16;   // uint4 units
                const size_t pb = (size_t)rec.y * 16;
                const size_t nb = (size_t)rec.z * 16;

                const uint4 A0 = tq[ab + ol];
                const uint4 A1 = tq[ab + 8 + ol];
                const uint4 P0 = tk[pb + ol];
                const uint4 P1 = tk[pb + 8 + ol];
                const uint4 N0 = tk[nb + ol];
                const uint4 N1 = tk[nb + 8 + ol];

                float d = 0.0f;
                acc_quad(A0, P0, N0, d);
                acc_quad(A1, P1, N1, d);
#pragma unroll
                for (int m = 1; m < 8; m <<= 1) d += __shfl_xor(d, m, 64);
                if (ol == 0) acc += fmaxf(d + MARGIN_F, 0.0f);
            }
        }
    }

    // block reduce (non-zero only on ol==0 lanes)
#pragma unroll
    for (int m = 1; m < 64; m <<= 1) acc += __shfl_xor(acc, m, 64);
    __shared__ float wsum[4];
    if ((t & 63) == 0) wsum[t >> 6] = acc;
    __syncthreads();
    if (t == 0) partials[blockIdx.x] = wsum[0] + wsum[1] + wsum[2] + wsum[3];
}

// ---------------------------------------------------------------------------
// Kernel 4: deterministic final reduction of block partials -> scalar out.
// ---------------------------------------------------------------------------
__global__ __launch_bounds__(256) void final_reduce(
    const float* __restrict__ partials, float* __restrict__ out)
{
    float s = 0.0f;
    for (int i = threadIdx.x; i < GATHER_BLOCKS; i += 256) s += partials[i];
#pragma unroll
    for (int m = 1; m < 64; m <<= 1) s += __shfl_xor(s, m, 64);
    __shared__ float ws4[4];
    if ((threadIdx.x & 63) == 0) ws4[threadIdx.x >> 6] = s;
    __syncthreads();
    if (threadIdx.x == 0) {
        const float invN = 1.0f / (1e-6f + (float)NSAMP);
        out[0] = (ws4[0] + ws4[1] + ws4[2] + ws4[3]) * invN;
    }
}

// ---------------------------------------------------------------------------
// Fallback (ws too small): direct strided gather in original layout.
// ---------------------------------------------------------------------------
__global__ __launch_bounds__(256) void triplet_direct(
    const float* __restrict__ q, const float* __restrict__ k,
    const int*  __restrict__ batch_idx,
    const int2* __restrict__ anchor_yx,
    const int2* __restrict__ pos_yx,
    const int2* __restrict__ neg_yx,
    float* __restrict__ out)
{
    const int lane   = threadIdx.x & 63;
    const int wid    = threadIdx.x >> 6;
    const int gwave  = blockIdx.x * 4 + wid;
    const int nwaves = gridDim.x * 4;

    float wsum = 0.0f;
    for (int i = gwave; i < NSAMP; i += nwaves) {
        const int  b  = batch_idx[i];
        const int2 ay = anchor_yx[i];
        const int2 py = pos_yx[i];
        const int2 ny = neg_yx[i];

        const size_t base = (size_t)b * NC * NS;
        const int sa = ay.x * FW + ay.y;
        const int sp = py.x * FW + py.y;
        const int sn = ny.x * FW + ny.y;

        float d = 0.0f;
#pragma unroll
        for (int kk = 0; kk < 4; ++kk) {
            const int c = lane + 64 * kk;
            const float av = q[base + (size_t)c * NS + sa];
            const float pv = k[base + (size_t)c * NS + sp];
            const float nv = k[base + (size_t)c * NS + sn];
            float t;
            t = av - pv; d += t * t;
            t = av - nv; d -= t * t;
        }
#pragma unroll
        for (int m = 1; m < 64; m <<= 1) d += __shfl_xor(d, m, 64);
        if (lane == 0) wsum += fmaxf(d + MARGIN_F, 0.0f);
    }

    __shared__ float bsum[4];
    if (lane == 0) bsum[wid] = wsum;
    __syncthreads();
    if (threadIdx.x == 0) {
        const float invN = 1.0f / (1e-6f + (float)NSAMP);
        atomicAdd(out, (bsum[0] + bsum[1] + bsum[2] + bsum[3]) * invN);
    }
}

extern "C" void kernel_launch(void* const* d_in, const int* in_sizes, int n_in,
                              void* d_out, int out_size, void* d_ws, size_t ws_size,
                              hipStream_t stream)
{
    const float* sketch = (const float*)d_in[0];
    const float* refk   = (const float*)d_in[1];
    const int*   bidx   = (const int*)d_in[2];
    const int2*  ayx    = (const int2*)d_in[3];
    const int2*  pyx    = (const int2*)d_in[4];
    const int2*  nyx    = (const int2*)d_in[5];
    float*       out    = (float*)d_out;

    const size_t tensor_elems = (size_t)NB * NC * NS;                    // 8M (8 MB fp8 each)
    const size_t recs_bytes   = (size_t)NB * BUCKET_CAP * sizeof(uint4); // 16 MB
    const size_t ctrl_uints   = 8 + 8 * 32;                              // counts + cursors
    const size_t need = 2 * tensor_elems + recs_bytes + ctrl_uints * 4
                      + GATHER_BLOCKS * sizeof(float);

    if (ws_size >= need) {
        unsigned char* tq = (unsigned char*)d_ws;
        unsigned char* tk = tq + tensor_elems;
        uint4* recs       = (uint4*)(tk + tensor_elems);
        unsigned* counts  = (unsigned*)((unsigned char*)recs + recs_bytes);
        unsigned* ccur    = counts + 8;
        float* partials   = (float*)(ccur + 8 * 32);

        (void)hipMemsetAsync(counts, 0, ctrl_uints * sizeof(unsigned), stream);

        dim3 tgrid(NS / 64, NC / 64, 16);   // 64 x 4 x 16
        transpose_to_bsc_fp8<<<tgrid, 256, 0, stream>>>(sketch, refk, tq, tk);

        bucket_samples<<<NSAMP / 256, 256, 0, stream>>>(
            bidx, ayx, pyx, nyx, recs, counts);

        triplet_gather_xcd<<<GATHER_BLOCKS, 256, 0, stream>>>(
            (const uint4*)tq, (const uint4*)tk, recs, counts, ccur, partials);

        final_reduce<<<1, 256, 0, stream>>>(partials, out);
    } else {
        (void)hipMemsetAsync(out, 0, sizeof(float), stream);
        triplet_direct<<<4096, 256, 0, stream>>>(
            sketch, refk, bidx, ayx, pyx, nyx, out);
    }
}